// Round 15
// baseline (617.186 us; speedup 1.0000x reference)
//
#include <hip/hip_runtime.h>

// ---------------------------------------------------------------------------
// SVT channel/token mixing: dwconv (ch 0..63) + DTCWT fwd -> channel mix ->
// token mix -> DTCWT inv (ch 64..127).  B=256, H=W=28, C=128, Ch=64.
// Round 15: apply the proven VGPR lever to k_fwdcol: fuse the e0/e1
// intermediate arrays into the band-write loop (each band pair i needs only
// e[2i], e[2i+1] -> compute 4 dot-products on the fly from the register-
// resident v window). Live floats 112 -> ~70, est VGPR ~160 -> ~90, waves
// 3 -> 5-6 per SIMD. Same FMA count and per-output order -> bitwise
// identical. k_mix (R13 form, 201-221us) and other kernels unchanged.
// ---------------------------------------------------------------------------

#define DI __device__ __forceinline__

__device__ constexpr float F_H0[13] = {
  -0.0017578f, 0.0f, 0.0222656f, -0.046875f, -0.0482422f, 0.296875f,
   0.5554688f, 0.296875f, -0.0482422f, -0.046875f, 0.0222656f, 0.0f, -0.0017578f};
__device__ constexpr float F_H1[19] = {
  -7.06e-05f, 0.0f, 0.0013419f, -0.0018834f, -0.0071568f, 0.023856f,
   0.0556431f, -0.0516881f, -0.2997576f, 0.5594308f, -0.2997576f, -0.0516881f,
   0.0556431f, 0.023856f, -0.0071568f, -0.0018834f, 0.0013419f, 0.0f, -7.06e-05f};
// g0 = h1 * sgn19 (+1 odd idx), g1 = -(h0 * sgn13) (+1 even idx)
__device__ constexpr float F_G0[19] = {
   7.06e-05f, 0.0f, -0.0013419f, -0.0018834f, 0.0071568f, 0.023856f,
  -0.0556431f, -0.0516881f, 0.2997576f, 0.5594308f, 0.2997576f, -0.0516881f,
  -0.0556431f, 0.023856f, 0.0071568f, -0.0018834f, -0.0013419f, 0.0f, 7.06e-05f};
__device__ constexpr float F_G1[13] = {
   0.0017578f, 0.0f, -0.0222656f, -0.046875f, 0.0482422f, 0.296875f,
  -0.5554688f, 0.296875f, 0.0482422f, -0.046875f, -0.0222656f, 0.0f, 0.0017578f};

DI constexpr int refl28(int i) { return i < 0 ? -1 - i : (i >= 28 ? 55 - i : i); }

#define S2C 0.70710678118654752f

// ---------------- K2: row filter (along W), line form ----------------------
__global__ __launch_bounds__(256) void k_rowfilt(const float* __restrict__ x,
    float* __restrict__ lo, float* __restrict__ hi) {
  int tid = threadIdx.x;
  int c = tid & 63;
  int line = blockIdx.x * 4 + (tid >> 6);     // line = b*28 + h, [0, 7168)
  const float* xp = x + (size_t)line * 28 * 128 + 64 + c;
  float v[28];
#pragma unroll
  for (int w = 0; w < 28; w++) v[w] = xp[w * 128];
  float* lp = lo + (size_t)line * 28 * 64 + c;
  float* hp = hi + (size_t)line * 28 * 64 + c;
#pragma unroll
  for (int w = 0; w < 28; w++) {
    float aLo = 0.f, aHi = 0.f;
#pragma unroll
    for (int t = 0; t < 13; t++) aLo = fmaf(F_H0[t], v[refl28(w - 6 + t)], aLo);
#pragma unroll
    for (int t = 0; t < 19; t++) aHi = fmaf(F_H1[t], v[refl28(w - 9 + t)], aHi);
    lp[w * 64] = aLo;
    hp[w * 64] = aHi;
  }
}

// ------- K3: merged column filter: blocks 0..895 = A (lo), 896..1791 = B ---
// Band outputs computed per-pair (no e0/e1 arrays) -> ~70 live floats.
__global__ __launch_bounds__(256) void k_fwdcol(const float* __restrict__ lo,
    const float* __restrict__ hi, const float* __restrict__ wll,
    float* __restrict__ xl, float* __restrict__ xhr, float* __restrict__ xhi) {
  __shared__ float swll[3584];                 // [(h*2+woff)*64 + c] (A only)
  int tid = threadIdx.x;
  if (blockIdx.x < 896) {
    // ---- A: lo -> xl (wll) + bands 0,5 ----
    int bid = blockIdx.x;
    int w2 = bid >> 6;
    for (int j = tid; j < 3584; j += 256) {
      int cc = j & 63, t = j >> 6;
      int h = t >> 1, woff = t & 1;
      swll[j] = wll[cc * 784 + h * 28 + 2 * w2 + woff];
    }
    __syncthreads();
    int c = tid & 63;
    int unit = bid * 4 + (tid >> 6);           // w2*256 + b
    int b = unit & 255;
    const int hs = 28 * 64;
    int base_in = (b * 784 + 2 * w2) * 64 + c;
    float v0[28], v1[28];
#pragma unroll
    for (int h = 0; h < 28; h++) {
      v0[h] = lo[base_in + h * hs];
      v1[h] = lo[base_in + h * hs + 64];
    }
#pragma unroll
    for (int h = 0; h < 28; h++) {
      float a0 = 0.f, a1 = 0.f;
#pragma unroll
      for (int t = 0; t < 13; t++) {
        a0 = fmaf(F_H0[t], v0[refl28(h - 6 + t)], a0);
        a1 = fmaf(F_H0[t], v1[refl28(h - 6 + t)], a1);
      }
      int o = (b * 784 + h * 28 + 2 * w2) * 64 + c;
      xl[o]      = a0 * swll[(h * 2 + 0) * 64 + c];
      xl[o + 64] = a1 * swll[(h * 2 + 1) * 64 + c];
    }
    // bands 0 (lhp), 5 (lhq): fused per-pair H1 filter
    {
      int bb = (b * 6 * 196 + w2) * 64 + c;
#pragma unroll
      for (int i = 0; i < 14; i++) {
        float A = 0.f, Bv = 0.f, C = 0.f, D = 0.f;   // e0[2i], e1[2i], e0[2i+1], e1[2i+1]
#pragma unroll
        for (int t = 0; t < 19; t++) {
          A  = fmaf(F_H1[t], v0[refl28(2 * i - 9 + t)], A);
          Bv = fmaf(F_H1[t], v1[refl28(2 * i - 9 + t)], Bv);
          C  = fmaf(F_H1[t], v0[refl28(2 * i + 1 - 9 + t)], C);
          D  = fmaf(F_H1[t], v1[refl28(2 * i + 1 - 9 + t)], D);
        }
        xhr[bb + 0 * 12544 + i * 896] = (A - D) * S2C;
        xhi[bb + 0 * 12544 + i * 896] = (Bv + C) * S2C;
        xhr[bb + 5 * 12544 + i * 896] = (A + D) * S2C;
        xhi[bb + 5 * 12544 + i * 896] = (Bv - C) * S2C;
      }
    }
  } else {
    // ---- B: hi -> bands 2,3 (H0) + 1,4 (H1), fused per-pair ----
    int bid = blockIdx.x - 896;
    int w2 = bid >> 6;
    int c = tid & 63;
    int unit = bid * 4 + (tid >> 6);
    int b = unit & 255;
    const int hs = 28 * 64;
    int base_in = (b * 784 + 2 * w2) * 64 + c;
    float v0[28], v1[28];
#pragma unroll
    for (int h = 0; h < 28; h++) {
      v0[h] = hi[base_in + h * hs];
      v1[h] = hi[base_in + h * hs + 64];
    }
    int bb = (b * 6 * 196 + w2) * 64 + c;
    // bands 2 (hlp), 3 (hlq): H0 filter
#pragma unroll
    for (int i = 0; i < 14; i++) {
      float A = 0.f, Bv = 0.f, C = 0.f, D = 0.f;
#pragma unroll
      for (int t = 0; t < 13; t++) {
        A  = fmaf(F_H0[t], v0[refl28(2 * i - 6 + t)], A);
        Bv = fmaf(F_H0[t], v1[refl28(2 * i - 6 + t)], Bv);
        C  = fmaf(F_H0[t], v0[refl28(2 * i + 1 - 6 + t)], C);
        D  = fmaf(F_H0[t], v1[refl28(2 * i + 1 - 6 + t)], D);
      }
      xhr[bb + 2 * 12544 + i * 896] = (A - D) * S2C;
      xhi[bb + 2 * 12544 + i * 896] = (Bv + C) * S2C;
      xhr[bb + 3 * 12544 + i * 896] = (A + D) * S2C;
      xhi[bb + 3 * 12544 + i * 896] = (Bv - C) * S2C;
    }
    // bands 1 (hhp), 4 (hhq): H1 filter
#pragma unroll
    for (int i = 0; i < 14; i++) {
      float A = 0.f, Bv = 0.f, C = 0.f, D = 0.f;
#pragma unroll
      for (int t = 0; t < 19; t++) {
        A  = fmaf(F_H1[t], v0[refl28(2 * i - 9 + t)], A);
        Bv = fmaf(F_H1[t], v1[refl28(2 * i - 9 + t)], Bv);
        C  = fmaf(F_H1[t], v0[refl28(2 * i + 1 - 9 + t)], C);
        D  = fmaf(F_H1[t], v1[refl28(2 * i + 1 - 9 + t)], D);
      }
      xhr[bb + 1 * 12544 + i * 896] = (A - D) * S2C;
      xhi[bb + 1 * 12544 + i * 896] = (Bv + C) * S2C;
      xhr[bb + 4 * 12544 + i * 896] = (A + D) * S2C;
      xhi[bb + 4 * 12544 + i * 896] = (Bv - C) * S2C;
    }
  }
}

// -------- K4: fused channel mix + token mix, ONE tile-pair per block -------
// grid 10752 = 128 pair-groups x 84 (band,h2). VGPR 80, occ ~33%.
__global__ __launch_bounds__(256) void k_mix(float* __restrict__ xhr,
    float* __restrict__ xhi,
    const float* __restrict__ w1, const float* __restrict__ w2,
    const float* __restrict__ b1, const float* __restrict__ b2,
    const float* __restrict__ wt1, const float* __restrict__ wt2,
    const float* __restrict__ bt1, const float* __restrict__ bt2) {
  __shared__ __align__(16) float sw1[2048];
  __shared__ __align__(16) float sw2[2048];
  __shared__ __align__(16) float sb1[128];
  __shared__ __align__(16) float sb2[128];
  __shared__ __align__(16) float sT1[784];
  __shared__ __align__(16) float sT2[784];
  __shared__ __align__(16) float sB1[28];
  __shared__ __align__(16) float sB2[28];
  const int S = 66;
  __shared__ __align__(16) float sXr0[14 * 66], sXi0[14 * 66];
  __shared__ __align__(16) float sXr1[14 * 66], sXi1[14 * 66];

  int tid = threadIdx.x;
  int n = blockIdx.x;                          // [0, 10752): p*84 + bh
  int p = n / 84; int bh = n - p * 84;
  int band = bh / 14; int h2 = bh - band * 14;
  size_t tb = (size_t)band * 12544 + (size_t)h2 * 896;

  for (int i = tid; i < 1024; i += 256) {
    int dk = i >> 2, blk = i & 3;
    int li = dk * 8 + blk * 2;
    sw1[li]     = w1[blk * 256 + dk];
    sw1[li + 1] = w1[1024 + blk * 256 + dk];
    sw2[li]     = w2[blk * 256 + dk];
    sw2[li + 1] = w2[1024 + blk * 256 + dk];
  }
  if (tid < 64) {
    int k = tid >> 2, blk = tid & 3;
    int li = k * 8 + blk * 2;
    sb1[li] = b1[blk * 16 + k]; sb1[li + 1] = b1[64 + blk * 16 + k];
    sb2[li] = b2[blk * 16 + k]; sb2[li + 1] = b2[64 + blk * 16 + k];
  }
  for (int i = tid; i < 196; i += 256) {
    sT1[2 * i] = wt1[h2 * 196 + i]; sT1[2 * i + 1] = wt1[2744 + h2 * 196 + i];
    sT2[2 * i] = wt2[h2 * 196 + i]; sT2[2 * i + 1] = wt2[2744 + h2 * 196 + i];
  }
  if (tid < 14) {
    sB1[2 * tid] = bt1[h2 * 14 + tid]; sB1[2 * tid + 1] = bt1[196 + h2 * 14 + tid];
    sB2[2 * tid] = bt2[h2 * 14 + tid]; sB2[2 * tid + 1] = bt2[196 + h2 * 14 + tid];
  }
  __syncthreads();

  int kq = tid / 56;                           // 0..3  (tid < 224)
  int task = tid - kq * 56;                    // 0..55
  int cw2 = task >> 2, cblk = task & 3;
  int wb = cblk * 2;
  int c = tid & 63;
  int tkq = tid >> 6;                          // 0..3 -> k = tkq*4 + kk

  size_t base0 = (size_t)(p * 2) * 75264 + tb;
  size_t base1 = base0 + 75264;

  // ---- phase 1a: chmix layer 1 (relu) -> sX (holds L1), both tiles ----
  if (tid < 224) {
    float xr0[16], xi0[16], xr1[16], xi1[16];
    const float4* pr0 = (const float4*)(xhr + base0 + cw2 * 64 + cblk * 16);
    const float4* pi0 = (const float4*)(xhi + base0 + cw2 * 64 + cblk * 16);
    const float4* pr1 = (const float4*)(xhr + base1 + cw2 * 64 + cblk * 16);
    const float4* pi1 = (const float4*)(xhi + base1 + cw2 * 64 + cblk * 16);
#pragma unroll
    for (int j = 0; j < 4; j++) {
      float4 a0 = pr0[j];
      xr0[4 * j] = a0.x; xr0[4 * j + 1] = a0.y; xr0[4 * j + 2] = a0.z; xr0[4 * j + 3] = a0.w;
      float4 b0 = pi0[j];
      xi0[4 * j] = b0.x; xi0[4 * j + 1] = b0.y; xi0[4 * j + 2] = b0.z; xi0[4 * j + 3] = b0.w;
      float4 a1 = pr1[j];
      xr1[4 * j] = a1.x; xr1[4 * j + 1] = a1.y; xr1[4 * j + 2] = a1.z; xr1[4 * j + 3] = a1.w;
      float4 b1v = pi1[j];
      xi1[4 * j] = b1v.x; xi1[4 * j + 1] = b1v.y; xi1[4 * j + 2] = b1v.z; xi1[4 * j + 3] = b1v.w;
    }
    float yr0[4], yi0[4], yr1[4], yi1[4];
#pragma unroll
    for (int kk = 0; kk < 4; kk++) {
      int k = kq * 4 + kk;
      float2 bv = *(const float2*)(sb1 + k * 8 + wb);
      float ar0 = bv.x, ai0 = bv.y, ar1 = bv.x, ai1 = bv.y;
#pragma unroll
      for (int d = 0; d < 16; d++) {
        float2 wv = *(const float2*)(sw1 + (d * 16 + k) * 8 + wb);
        ar0 = fmaf(xr0[d], wv.x, ar0); ar0 = fmaf(-xi0[d], wv.y, ar0);
        ai0 = fmaf(xr0[d], wv.y, ai0); ai0 = fmaf(xi0[d], wv.x, ai0);
        ar1 = fmaf(xr1[d], wv.x, ar1); ar1 = fmaf(-xi1[d], wv.y, ar1);
        ai1 = fmaf(xr1[d], wv.y, ai1); ai1 = fmaf(xi1[d], wv.x, ai1);
      }
      yr0[kk] = fmaxf(ar0, 0.f); yi0[kk] = fmaxf(ai0, 0.f);
      yr1[kk] = fmaxf(ar1, 0.f); yi1[kk] = fmaxf(ai1, 0.f);
    }
    int yo = cw2 * S + cblk * 16 + kq * 4;
    *(float4*)(sXr0 + yo) = make_float4(yr0[0], yr0[1], yr0[2], yr0[3]);
    *(float4*)(sXi0 + yo) = make_float4(yi0[0], yi0[1], yi0[2], yi0[3]);
    *(float4*)(sXr1 + yo) = make_float4(yr1[0], yr1[1], yr1[2], yr1[3]);
    *(float4*)(sXi1 + yo) = make_float4(yi1[0], yi1[1], yi1[2], yi1[3]);
  }
  __syncthreads();

  // ---- phase 1b: read own 16ch L1 -> regs; barrier; L2 -> sX ----
  float yr0[16], yi0[16], yr1[16], yi1[16];
  if (tid < 224) {
    int yb = cw2 * S + cblk * 16;
#pragma unroll
    for (int j = 0; j < 4; j++) {
      float4 a0 = *(const float4*)(sXr0 + yb + 4 * j);
      yr0[4 * j] = a0.x; yr0[4 * j + 1] = a0.y; yr0[4 * j + 2] = a0.z; yr0[4 * j + 3] = a0.w;
      float4 b0 = *(const float4*)(sXi0 + yb + 4 * j);
      yi0[4 * j] = b0.x; yi0[4 * j + 1] = b0.y; yi0[4 * j + 2] = b0.z; yi0[4 * j + 3] = b0.w;
      float4 a1 = *(const float4*)(sXr1 + yb + 4 * j);
      yr1[4 * j] = a1.x; yr1[4 * j + 1] = a1.y; yr1[4 * j + 2] = a1.z; yr1[4 * j + 3] = a1.w;
      float4 b1v = *(const float4*)(sXi1 + yb + 4 * j);
      yi1[4 * j] = b1v.x; yi1[4 * j + 1] = b1v.y; yi1[4 * j + 2] = b1v.z; yi1[4 * j + 3] = b1v.w;
    }
  }
  __syncthreads();
  if (tid < 224) {
    float zr0[4], zi0[4], zr1[4], zi1[4];
#pragma unroll
    for (int kk = 0; kk < 4; kk++) {
      int k = kq * 4 + kk;
      float2 bv = *(const float2*)(sb2 + k * 8 + wb);
      float ar0 = bv.x, ai0 = bv.y, ar1 = bv.x, ai1 = bv.y;
#pragma unroll
      for (int d = 0; d < 16; d++) {
        float2 wv = *(const float2*)(sw2 + (d * 16 + k) * 8 + wb);
        ar0 = fmaf(yr0[d], wv.x, ar0); ar0 = fmaf(-yi0[d], wv.y, ar0);
        ai0 = fmaf(yr0[d], wv.y, ai0); ai0 = fmaf(yi0[d], wv.x, ai0);
        ar1 = fmaf(yr1[d], wv.x, ar1); ar1 = fmaf(-yi1[d], wv.y, ar1);
        ai1 = fmaf(yr1[d], wv.y, ai1); ai1 = fmaf(yi1[d], wv.x, ai1);
      }
      zr0[kk] = ar0; zi0[kk] = ai0; zr1[kk] = ar1; zi1[kk] = ai1;
    }
    int yo = cw2 * S + cblk * 16 + kq * 4;
    *(float4*)(sXr0 + yo) = make_float4(zr0[0], zr0[1], zr0[2], zr0[3]);
    *(float4*)(sXi0 + yo) = make_float4(zi0[0], zi0[1], zi0[2], zi0[3]);
    *(float4*)(sXr1 + yo) = make_float4(zr1[0], zr1[1], zr1[2], zr1[3]);
    *(float4*)(sXi1 + yo) = make_float4(zi1[0], zi1[1], zi1[2], zi1[3]);
  }
  __syncthreads();

  // ---- phase 2a: read column c -> regs; barrier; token L1 -> sX [14][64]
  {
    float tr0[14], ti0[14], tr1[14], ti1[14];
#pragma unroll
    for (int d = 0; d < 14; d++) {
      tr0[d] = sXr0[d * S + c]; ti0[d] = sXi0[d * S + c];
      tr1[d] = sXr1[d * S + c]; ti1[d] = sXi1[d * S + c];
    }
    __syncthreads();
#pragma unroll
    for (int kk = 0; kk < 4; kk++) {
      int k = tkq * 4 + kk;
      if (k < 14) {
        float br = sB1[2 * k], bi = sB1[2 * k + 1];
        float ar0 = br, ai0 = bi, ar1 = br, ai1 = bi;
#pragma unroll
        for (int d = 0; d < 14; d++) {
          float wr = sT1[(d * 14 + k) * 2], wi = sT1[(d * 14 + k) * 2 + 1];
          ar0 = fmaf(tr0[d], wr, ar0); ar0 = fmaf(-ti0[d], wi, ar0);
          ai0 = fmaf(tr0[d], wi, ai0); ai0 = fmaf(ti0[d], wr, ai0);
          ar1 = fmaf(tr1[d], wr, ar1); ar1 = fmaf(-ti1[d], wi, ar1);
          ai1 = fmaf(tr1[d], wi, ai1); ai1 = fmaf(ti1[d], wr, ai1);
        }
        sXr0[k * 64 + c] = fmaxf(ar0, 0.f); sXi0[k * 64 + c] = fmaxf(ai0, 0.f);
        sXr1[k * 64 + c] = fmaxf(ar1, 0.f); sXi1[k * 64 + c] = fmaxf(ai1, 0.f);
      }
    }
  }
  __syncthreads();

  // ---- phase 2b: token L2 -> global, both tiles ----
  {
    float mr0[14], mi0[14], mr1[14], mi1[14];
#pragma unroll
    for (int d = 0; d < 14; d++) {
      mr0[d] = sXr0[d * 64 + c]; mi0[d] = sXi0[d * 64 + c];
      mr1[d] = sXr1[d * 64 + c]; mi1[d] = sXi1[d * 64 + c];
    }
#pragma unroll
    for (int kk = 0; kk < 4; kk++) {
      int k = tkq * 4 + kk;
      if (k < 14) {
        float br = sB2[2 * k], bi = sB2[2 * k + 1];
        float ar0 = br, ai0 = bi, ar1 = br, ai1 = bi;
#pragma unroll
        for (int d = 0; d < 14; d++) {
          float wr = sT2[(d * 14 + k) * 2], wi = sT2[(d * 14 + k) * 2 + 1];
          ar0 = fmaf(mr0[d], wr, ar0); ar0 = fmaf(-mi0[d], wi, ar0);
          ai0 = fmaf(mr0[d], wi, ai0); ai0 = fmaf(mi0[d], wr, ai0);
          ar1 = fmaf(mr1[d], wr, ar1); ar1 = fmaf(-mi1[d], wi, ar1);
          ai1 = fmaf(mr1[d], wi, ai1); ai1 = fmaf(mi1[d], wr, ai1);
        }
        xhr[base0 + k * 64 + c] = ar0; xhi[base0 + k * 64 + c] = ai0;
        xhr[base1 + k * 64 + c] = ar1; xhi[base1 + k * 64 + c] = ai1;
      }
    }
  }
}

// -------- K5: merged inverse column: blocks 0..1791 = A, 1792..3583 = B ----
__global__ __launch_bounds__(256) void k_invcol2(const float* __restrict__ xl,
    const float* __restrict__ xhr, const float* __restrict__ xhi,
    float* __restrict__ lo2, float* __restrict__ hi2) {
  int tid = threadIdx.x;
  int c = tid & 63;
  if (blockIdx.x < 1792) {
    // ---- A: pass 1 -> lo2 ----
    int line = blockIdx.x * 4 + (tid >> 6);    // line = b*28 + w
    int w = line % 28, b = line / 28;
    int w2 = w >> 1, pw = w & 1;
    const int hs = 28 * 64;
    int sp = (b * 784 + w) * 64 + c;
    int bb = (b * 6 * 196 + w2) * 64 + c;
    float xlv[28], lhf[28];
#pragma unroll
    for (int h = 0; h < 28; h++) xlv[h] = xl[sp + h * hs];
    const float* p0r = xhr + bb + 0 * 12544;
    const float* p0i = xhi + bb + 0 * 12544;
    const float* p5r = xhr + bb + 5 * 12544;
    const float* p5i = xhi + bb + 5 * 12544;
#pragma unroll
    for (int i = 0; i < 14; i++) {
      float y0r = p0r[i * 896], y0i = p0i[i * 896];
      float y5r = p5r[i * 896], y5i = p5i[i * 896];
      float top, bot;
      if (pw) { top = y0i + y5i; bot = y5r - y0r; }
      else    { top = y0r + y5r; bot = y0i - y5i; }
      lhf[2 * i] = top * S2C; lhf[2 * i + 1] = bot * S2C;
    }
#pragma unroll
    for (int h = 0; h < 28; h++) {
      float acc = 0.f;
#pragma unroll
      for (int t = 0; t < 19; t++) acc = fmaf(F_G0[t], xlv[refl28(h - 9 + t)], acc);
#pragma unroll
      for (int t = 0; t < 13; t++) acc = fmaf(F_G1[t], lhf[refl28(h - 6 + t)], acc);
      lo2[sp + h * hs] = acc;
    }
  } else {
    // ---- B: pass 2 -> hi2 ----
    int line = (blockIdx.x - 1792) * 4 + (tid >> 6);
    int w = line % 28, b = line / 28;
    int w2 = w >> 1, pw = w & 1;
    const int hs = 28 * 64;
    int sp = (b * 784 + w) * 64 + c;
    int bb = (b * 6 * 196 + w2) * 64 + c;
    float hlC[28], hhD[28];
    const float* p2r = xhr + bb + 2 * 12544;
    const float* p2i = xhi + bb + 2 * 12544;
    const float* p3r = xhr + bb + 3 * 12544;
    const float* p3i = xhi + bb + 3 * 12544;
#pragma unroll
    for (int i = 0; i < 14; i++) {
      float y0r = p2r[i * 896], y0i = p2i[i * 896];
      float y5r = p3r[i * 896], y5i = p3i[i * 896];
      float top, bot;
      if (pw) { top = y0i + y5i; bot = y5r - y0r; }
      else    { top = y0r + y5r; bot = y0i - y5i; }
      hlC[2 * i] = top * S2C; hlC[2 * i + 1] = bot * S2C;
    }
    const float* p1r = xhr + bb + 1 * 12544;
    const float* p1i = xhi + bb + 1 * 12544;
    const float* p4r = xhr + bb + 4 * 12544;
    const float* p4i = xhi + bb + 4 * 12544;
#pragma unroll
    for (int i = 0; i < 14; i++) {
      float y0r = p1r[i * 896], y0i = p1i[i * 896];
      float y5r = p4r[i * 896], y5i = p4i[i * 896];
      float top, bot;
      if (pw) { top = y0i + y5i; bot = y5r - y0r; }
      else    { top = y0r + y5r; bot = y0i - y5i; }
      hhD[2 * i] = top * S2C; hhD[2 * i + 1] = bot * S2C;
    }
#pragma unroll
    for (int h = 0; h < 28; h++) {
      float acc = 0.f;
#pragma unroll
      for (int t = 0; t < 19; t++) acc = fmaf(F_G0[t], hlC[refl28(h - 9 + t)], acc);
#pragma unroll
      for (int t = 0; t < 13; t++) acc = fmaf(F_G1[t], hhD[refl28(h - 6 + t)], acc);
      hi2[sp + h * hs] = acc;
    }
  }
}

// ---- K6: merged inverse row filter (0..1791) + dwconv (1792..51967) -------
__global__ __launch_bounds__(256) void k_invrowdw(const float* __restrict__ lo2,
    const float* __restrict__ hi2, const float* __restrict__ x,
    const float* __restrict__ cw, const float* __restrict__ cb,
    float* __restrict__ out) {
  int tid = threadIdx.x;
  if (blockIdx.x < 1792) {
    // ---- inverse row filter ----
    int c = tid & 63;
    int line = blockIdx.x * 4 + (tid >> 6);    // line = b*28 + h
    const float* lr = lo2 + (size_t)line * 28 * 64 + c;
    const float* hr = hi2 + (size_t)line * 28 * 64 + c;
    float vl[28], vh[28];
#pragma unroll
    for (int w = 0; w < 28; w++) { vl[w] = lr[w * 64]; vh[w] = hr[w * 64]; }
    float* op = out + (size_t)line * 28 * 128 + 64 + c;
#pragma unroll
    for (int w = 0; w < 28; w++) {
      float acc = 0.f;
#pragma unroll
      for (int t = 0; t < 19; t++) acc = fmaf(F_G0[t], vl[refl28(w - 9 + t)], acc);
#pragma unroll
      for (int t = 0; t < 13; t++) acc = fmaf(F_G1[t], vh[refl28(w - 6 + t)], acc);
      op[w * 128] = acc;
    }
  } else {
    // ---- dwconv: depthwise 3x3, channels 0..63 ----
    int gtid = (blockIdx.x - 1792) * 256 + tid;
    int c = gtid & 63;
    int s = gtid >> 6;                 // b*784 + h*28 + w
    int w = s % 28; int t2 = s / 28; int h = t2 % 28;
    const float* k = cw + c * 9;
    const float* xb = x + (size_t)s * 128 + c;
    float acc = cb[c];
    bool hm = h > 0, hp = h < 27, wm = w > 0, wp = w < 27;
    if (hm) {
      const float* r = xb - 28 * 128;
      if (wm) acc = fmaf(r[-128], k[0], acc);
      acc = fmaf(r[0], k[1], acc);
      if (wp) acc = fmaf(r[128], k[2], acc);
    }
    if (wm) acc = fmaf(xb[-128], k[3], acc);
    acc = fmaf(xb[0], k[4], acc);
    if (wp) acc = fmaf(xb[128], k[5], acc);
    if (hp) {
      const float* r = xb + 28 * 128;
      if (wm) acc = fmaf(r[-128], k[6], acc);
      acc = fmaf(r[0], k[7], acc);
      if (wp) acc = fmaf(r[128], k[8], acc);
    }
    out[(size_t)s * 128 + c] = acc;
  }
}

// ---------------------------------------------------------------------------
extern "C" void kernel_launch(void* const* d_in, const int* in_sizes, int n_in,
                              void* d_out, int out_size, void* d_ws, size_t ws_size,
                              hipStream_t stream) {
  const float* x    = (const float*)d_in[0];
  const float* cw   = (const float*)d_in[1];
  const float* cb   = (const float*)d_in[2];
  const float* wll  = (const float*)d_in[3];
  const float* wlh1 = (const float*)d_in[4];
  const float* wlh2 = (const float*)d_in[5];
  const float* blh1 = (const float*)d_in[6];
  const float* blh2 = (const float*)d_in[7];
  const float* wt1  = (const float*)d_in[8];
  const float* wt2  = (const float*)d_in[9];
  const float* bt1  = (const float*)d_in[10];
  const float* bt2  = (const float*)d_in[11];
  float* out = (float*)d_out;
  float* ws = (float*)d_ws;

  const size_t NSP = (size_t)256 * 784 * 64;     // 12,845,056
  const size_t NXH = (size_t)256 * 6 * 196 * 64; // 19,267,584
  float* lo  = ws;              // reused as lo2 after fwdcol consumes it
  float* hi  = lo + NSP;        // reused as hi2
  float* xl  = hi + NSP;
  float* xhr = xl + NSP;
  float* xhi = xhr + NXH;       // total 308.3 MB

  dim3 blk(256);
  k_rowfilt <<<1792,  blk, 0, stream>>>(x, lo, hi);
  k_fwdcol  <<<1792,  blk, 0, stream>>>(lo, hi, wll, xl, xhr, xhi);
  k_mix     <<<10752, blk, 0, stream>>>(xhr, xhi, wlh1, wlh2, blh1, blh2,
                                        wt1, wt2, bt1, bt2);
  k_invcol2 <<<3584,  blk, 0, stream>>>(xl, xhr, xhi, lo, hi);
  k_invrowdw<<<51968, blk, 0, stream>>>(lo, hi, x, cw, cb, out);
  (void)in_sizes; (void)n_in; (void)out_size; (void)ws_size;
}

// Round 16
// 611.447 us; speedup vs baseline: 1.0094x; 1.0094x over previous
//
#include <hip/hip_runtime.h>

// ---------------------------------------------------------------------------
// SVT channel/token mixing: dwconv (ch 0..63) + DTCWT fwd -> channel mix ->
// token mix -> DTCWT inv (ch 64..127).  B=256, H=W=28, C=128, Ch=64.
// Round 16: double TLP on the latency-bound line filters (R11 proved TLP
// sensitivity in the inverse direction): rowfilt and the invrow branch
// split each line's 28 outputs across 2 threads (wave-uniform half index,
// both halves fully unrolled, 23-value load windows). Per-thread serial
// chain halves; read amplification 1.64x (+~15us BW at 12-17% HBM util).
// Per-output FMA order unchanged -> absmax identical. k_mix (R13 form),
// fwdcol (R15 fused), invcol2 unchanged.
// ---------------------------------------------------------------------------

#define DI __device__ __forceinline__

__device__ constexpr float F_H0[13] = {
  -0.0017578f, 0.0f, 0.0222656f, -0.046875f, -0.0482422f, 0.296875f,
   0.5554688f, 0.296875f, -0.0482422f, -0.046875f, 0.0222656f, 0.0f, -0.0017578f};
__device__ constexpr float F_H1[19] = {
  -7.06e-05f, 0.0f, 0.0013419f, -0.0018834f, -0.0071568f, 0.023856f,
   0.0556431f, -0.0516881f, -0.2997576f, 0.5594308f, -0.2997576f, -0.0516881f,
   0.0556431f, 0.023856f, -0.0071568f, -0.0018834f, 0.0013419f, 0.0f, -7.06e-05f};
// g0 = h1 * sgn19 (+1 odd idx), g1 = -(h0 * sgn13) (+1 even idx)
__device__ constexpr float F_G0[19] = {
   7.06e-05f, 0.0f, -0.0013419f, -0.0018834f, 0.0071568f, 0.023856f,
  -0.0556431f, -0.0516881f, 0.2997576f, 0.5594308f, 0.2997576f, -0.0516881f,
  -0.0556431f, 0.023856f, 0.0071568f, -0.0018834f, -0.0013419f, 0.0f, 7.06e-05f};
__device__ constexpr float F_G1[13] = {
   0.0017578f, 0.0f, -0.0222656f, -0.046875f, 0.0482422f, 0.296875f,
  -0.5554688f, 0.296875f, 0.0482422f, -0.046875f, -0.0222656f, 0.0f, 0.0017578f};

DI constexpr int refl28(int i) { return i < 0 ? -1 - i : (i >= 28 ? 55 - i : i); }

#define S2C 0.70710678118654752f

// ------- K2: row filter (along W), half-line form (2 threads/line) ---------
__global__ __launch_bounds__(256) void k_rowfilt(const float* __restrict__ x,
    float* __restrict__ lo, float* __restrict__ hi) {
  int tid = threadIdx.x;
  int c = tid & 63;
  int unit = blockIdx.x * 4 + (tid >> 6);     // [0, 14336): line*2 + half
  int line = unit >> 1;
  int half = unit & 1;                        // wave-uniform
  const float* xp = x + (size_t)line * 3584 + 64 + c;
  float* lp = lo + (size_t)line * 1792 + c;
  float* hp = hi + (size_t)line * 1792 + c;
  if (half == 0) {
    float v[23];                              // v[0..22]
#pragma unroll
    for (int j = 0; j < 23; j++) v[j] = xp[j * 128];
#pragma unroll
    for (int w = 0; w < 14; w++) {
      float aLo = 0.f, aHi = 0.f;
#pragma unroll
      for (int t = 0; t < 13; t++) aLo = fmaf(F_H0[t], v[refl28(w - 6 + t)], aLo);
#pragma unroll
      for (int t = 0; t < 19; t++) aHi = fmaf(F_H1[t], v[refl28(w - 9 + t)], aHi);
      lp[w * 64] = aLo;
      hp[w * 64] = aHi;
    }
  } else {
    float v[23];                              // v[j] = orig v[j+5]
#pragma unroll
    for (int j = 0; j < 23; j++) v[j] = xp[(j + 5) * 128];
#pragma unroll
    for (int w = 14; w < 28; w++) {
      float aLo = 0.f, aHi = 0.f;
#pragma unroll
      for (int t = 0; t < 13; t++) aLo = fmaf(F_H0[t], v[refl28(w - 6 + t) - 5], aLo);
#pragma unroll
      for (int t = 0; t < 19; t++) aHi = fmaf(F_H1[t], v[refl28(w - 9 + t) - 5], aHi);
      lp[w * 64] = aLo;
      hp[w * 64] = aHi;
    }
  }
}

// ------- K3: merged column filter: blocks 0..895 = A (lo), 896..1791 = B ---
// Band outputs computed per-pair (no e0/e1 arrays).
__global__ __launch_bounds__(256) void k_fwdcol(const float* __restrict__ lo,
    const float* __restrict__ hi, const float* __restrict__ wll,
    float* __restrict__ xl, float* __restrict__ xhr, float* __restrict__ xhi) {
  __shared__ float swll[3584];                 // [(h*2+woff)*64 + c] (A only)
  int tid = threadIdx.x;
  if (blockIdx.x < 896) {
    // ---- A: lo -> xl (wll) + bands 0,5 ----
    int bid = blockIdx.x;
    int w2 = bid >> 6;
    for (int j = tid; j < 3584; j += 256) {
      int cc = j & 63, t = j >> 6;
      int h = t >> 1, woff = t & 1;
      swll[j] = wll[cc * 784 + h * 28 + 2 * w2 + woff];
    }
    __syncthreads();
    int c = tid & 63;
    int unit = bid * 4 + (tid >> 6);           // w2*256 + b
    int b = unit & 255;
    const int hs = 28 * 64;
    int base_in = (b * 784 + 2 * w2) * 64 + c;
    float v0[28], v1[28];
#pragma unroll
    for (int h = 0; h < 28; h++) {
      v0[h] = lo[base_in + h * hs];
      v1[h] = lo[base_in + h * hs + 64];
    }
#pragma unroll
    for (int h = 0; h < 28; h++) {
      float a0 = 0.f, a1 = 0.f;
#pragma unroll
      for (int t = 0; t < 13; t++) {
        a0 = fmaf(F_H0[t], v0[refl28(h - 6 + t)], a0);
        a1 = fmaf(F_H0[t], v1[refl28(h - 6 + t)], a1);
      }
      int o = (b * 784 + h * 28 + 2 * w2) * 64 + c;
      xl[o]      = a0 * swll[(h * 2 + 0) * 64 + c];
      xl[o + 64] = a1 * swll[(h * 2 + 1) * 64 + c];
    }
    // bands 0 (lhp), 5 (lhq): fused per-pair H1 filter
    {
      int bb = (b * 6 * 196 + w2) * 64 + c;
#pragma unroll
      for (int i = 0; i < 14; i++) {
        float A = 0.f, Bv = 0.f, C = 0.f, D = 0.f;
#pragma unroll
        for (int t = 0; t < 19; t++) {
          A  = fmaf(F_H1[t], v0[refl28(2 * i - 9 + t)], A);
          Bv = fmaf(F_H1[t], v1[refl28(2 * i - 9 + t)], Bv);
          C  = fmaf(F_H1[t], v0[refl28(2 * i + 1 - 9 + t)], C);
          D  = fmaf(F_H1[t], v1[refl28(2 * i + 1 - 9 + t)], D);
        }
        xhr[bb + 0 * 12544 + i * 896] = (A - D) * S2C;
        xhi[bb + 0 * 12544 + i * 896] = (Bv + C) * S2C;
        xhr[bb + 5 * 12544 + i * 896] = (A + D) * S2C;
        xhi[bb + 5 * 12544 + i * 896] = (Bv - C) * S2C;
      }
    }
  } else {
    // ---- B: hi -> bands 2,3 (H0) + 1,4 (H1), fused per-pair ----
    int bid = blockIdx.x - 896;
    int w2 = bid >> 6;
    int c = tid & 63;
    int unit = bid * 4 + (tid >> 6);
    int b = unit & 255;
    const int hs = 28 * 64;
    int base_in = (b * 784 + 2 * w2) * 64 + c;
    float v0[28], v1[28];
#pragma unroll
    for (int h = 0; h < 28; h++) {
      v0[h] = hi[base_in + h * hs];
      v1[h] = hi[base_in + h * hs + 64];
    }
    int bb = (b * 6 * 196 + w2) * 64 + c;
#pragma unroll
    for (int i = 0; i < 14; i++) {
      float A = 0.f, Bv = 0.f, C = 0.f, D = 0.f;
#pragma unroll
      for (int t = 0; t < 13; t++) {
        A  = fmaf(F_H0[t], v0[refl28(2 * i - 6 + t)], A);
        Bv = fmaf(F_H0[t], v1[refl28(2 * i - 6 + t)], Bv);
        C  = fmaf(F_H0[t], v0[refl28(2 * i + 1 - 6 + t)], C);
        D  = fmaf(F_H0[t], v1[refl28(2 * i + 1 - 6 + t)], D);
      }
      xhr[bb + 2 * 12544 + i * 896] = (A - D) * S2C;
      xhi[bb + 2 * 12544 + i * 896] = (Bv + C) * S2C;
      xhr[bb + 3 * 12544 + i * 896] = (A + D) * S2C;
      xhi[bb + 3 * 12544 + i * 896] = (Bv - C) * S2C;
    }
#pragma unroll
    for (int i = 0; i < 14; i++) {
      float A = 0.f, Bv = 0.f, C = 0.f, D = 0.f;
#pragma unroll
      for (int t = 0; t < 19; t++) {
        A  = fmaf(F_H1[t], v0[refl28(2 * i - 9 + t)], A);
        Bv = fmaf(F_H1[t], v1[refl28(2 * i - 9 + t)], Bv);
        C  = fmaf(F_H1[t], v0[refl28(2 * i + 1 - 9 + t)], C);
        D  = fmaf(F_H1[t], v1[refl28(2 * i + 1 - 9 + t)], D);
      }
      xhr[bb + 1 * 12544 + i * 896] = (A - D) * S2C;
      xhi[bb + 1 * 12544 + i * 896] = (Bv + C) * S2C;
      xhr[bb + 4 * 12544 + i * 896] = (A + D) * S2C;
      xhi[bb + 4 * 12544 + i * 896] = (Bv - C) * S2C;
    }
  }
}

// -------- K4: fused channel mix + token mix, ONE tile-pair per block -------
// grid 10752 = 128 pair-groups x 84 (band,h2). VGPR 80, occ ~33%.
__global__ __launch_bounds__(256) void k_mix(float* __restrict__ xhr,
    float* __restrict__ xhi,
    const float* __restrict__ w1, const float* __restrict__ w2,
    const float* __restrict__ b1, const float* __restrict__ b2,
    const float* __restrict__ wt1, const float* __restrict__ wt2,
    const float* __restrict__ bt1, const float* __restrict__ bt2) {
  __shared__ __align__(16) float sw1[2048];
  __shared__ __align__(16) float sw2[2048];
  __shared__ __align__(16) float sb1[128];
  __shared__ __align__(16) float sb2[128];
  __shared__ __align__(16) float sT1[784];
  __shared__ __align__(16) float sT2[784];
  __shared__ __align__(16) float sB1[28];
  __shared__ __align__(16) float sB2[28];
  const int S = 66;
  __shared__ __align__(16) float sXr0[14 * 66], sXi0[14 * 66];
  __shared__ __align__(16) float sXr1[14 * 66], sXi1[14 * 66];

  int tid = threadIdx.x;
  int n = blockIdx.x;                          // [0, 10752): p*84 + bh
  int p = n / 84; int bh = n - p * 84;
  int band = bh / 14; int h2 = bh - band * 14;
  size_t tb = (size_t)band * 12544 + (size_t)h2 * 896;

  for (int i = tid; i < 1024; i += 256) {
    int dk = i >> 2, blk = i & 3;
    int li = dk * 8 + blk * 2;
    sw1[li]     = w1[blk * 256 + dk];
    sw1[li + 1] = w1[1024 + blk * 256 + dk];
    sw2[li]     = w2[blk * 256 + dk];
    sw2[li + 1] = w2[1024 + blk * 256 + dk];
  }
  if (tid < 64) {
    int k = tid >> 2, blk = tid & 3;
    int li = k * 8 + blk * 2;
    sb1[li] = b1[blk * 16 + k]; sb1[li + 1] = b1[64 + blk * 16 + k];
    sb2[li] = b2[blk * 16 + k]; sb2[li + 1] = b2[64 + blk * 16 + k];
  }
  for (int i = tid; i < 196; i += 256) {
    sT1[2 * i] = wt1[h2 * 196 + i]; sT1[2 * i + 1] = wt1[2744 + h2 * 196 + i];
    sT2[2 * i] = wt2[h2 * 196 + i]; sT2[2 * i + 1] = wt2[2744 + h2 * 196 + i];
  }
  if (tid < 14) {
    sB1[2 * tid] = bt1[h2 * 14 + tid]; sB1[2 * tid + 1] = bt1[196 + h2 * 14 + tid];
    sB2[2 * tid] = bt2[h2 * 14 + tid]; sB2[2 * tid + 1] = bt2[196 + h2 * 14 + tid];
  }
  __syncthreads();

  int kq = tid / 56;                           // 0..3  (tid < 224)
  int task = tid - kq * 56;                    // 0..55
  int cw2 = task >> 2, cblk = task & 3;
  int wb = cblk * 2;
  int c = tid & 63;
  int tkq = tid >> 6;                          // 0..3 -> k = tkq*4 + kk

  size_t base0 = (size_t)(p * 2) * 75264 + tb;
  size_t base1 = base0 + 75264;

  // ---- phase 1a: chmix layer 1 (relu) -> sX (holds L1), both tiles ----
  if (tid < 224) {
    float xr0[16], xi0[16], xr1[16], xi1[16];
    const float4* pr0 = (const float4*)(xhr + base0 + cw2 * 64 + cblk * 16);
    const float4* pi0 = (const float4*)(xhi + base0 + cw2 * 64 + cblk * 16);
    const float4* pr1 = (const float4*)(xhr + base1 + cw2 * 64 + cblk * 16);
    const float4* pi1 = (const float4*)(xhi + base1 + cw2 * 64 + cblk * 16);
#pragma unroll
    for (int j = 0; j < 4; j++) {
      float4 a0 = pr0[j];
      xr0[4 * j] = a0.x; xr0[4 * j + 1] = a0.y; xr0[4 * j + 2] = a0.z; xr0[4 * j + 3] = a0.w;
      float4 b0 = pi0[j];
      xi0[4 * j] = b0.x; xi0[4 * j + 1] = b0.y; xi0[4 * j + 2] = b0.z; xi0[4 * j + 3] = b0.w;
      float4 a1 = pr1[j];
      xr1[4 * j] = a1.x; xr1[4 * j + 1] = a1.y; xr1[4 * j + 2] = a1.z; xr1[4 * j + 3] = a1.w;
      float4 b1v = pi1[j];
      xi1[4 * j] = b1v.x; xi1[4 * j + 1] = b1v.y; xi1[4 * j + 2] = b1v.z; xi1[4 * j + 3] = b1v.w;
    }
    float yr0[4], yi0[4], yr1[4], yi1[4];
#pragma unroll
    for (int kk = 0; kk < 4; kk++) {
      int k = kq * 4 + kk;
      float2 bv = *(const float2*)(sb1 + k * 8 + wb);
      float ar0 = bv.x, ai0 = bv.y, ar1 = bv.x, ai1 = bv.y;
#pragma unroll
      for (int d = 0; d < 16; d++) {
        float2 wv = *(const float2*)(sw1 + (d * 16 + k) * 8 + wb);
        ar0 = fmaf(xr0[d], wv.x, ar0); ar0 = fmaf(-xi0[d], wv.y, ar0);
        ai0 = fmaf(xr0[d], wv.y, ai0); ai0 = fmaf(xi0[d], wv.x, ai0);
        ar1 = fmaf(xr1[d], wv.x, ar1); ar1 = fmaf(-xi1[d], wv.y, ar1);
        ai1 = fmaf(xr1[d], wv.y, ai1); ai1 = fmaf(xi1[d], wv.x, ai1);
      }
      yr0[kk] = fmaxf(ar0, 0.f); yi0[kk] = fmaxf(ai0, 0.f);
      yr1[kk] = fmaxf(ar1, 0.f); yi1[kk] = fmaxf(ai1, 0.f);
    }
    int yo = cw2 * S + cblk * 16 + kq * 4;
    *(float4*)(sXr0 + yo) = make_float4(yr0[0], yr0[1], yr0[2], yr0[3]);
    *(float4*)(sXi0 + yo) = make_float4(yi0[0], yi0[1], yi0[2], yi0[3]);
    *(float4*)(sXr1 + yo) = make_float4(yr1[0], yr1[1], yr1[2], yr1[3]);
    *(float4*)(sXi1 + yo) = make_float4(yi1[0], yi1[1], yi1[2], yi1[3]);
  }
  __syncthreads();

  // ---- phase 1b: read own 16ch L1 -> regs; barrier; L2 -> sX ----
  float yr0[16], yi0[16], yr1[16], yi1[16];
  if (tid < 224) {
    int yb = cw2 * S + cblk * 16;
#pragma unroll
    for (int j = 0; j < 4; j++) {
      float4 a0 = *(const float4*)(sXr0 + yb + 4 * j);
      yr0[4 * j] = a0.x; yr0[4 * j + 1] = a0.y; yr0[4 * j + 2] = a0.z; yr0[4 * j + 3] = a0.w;
      float4 b0 = *(const float4*)(sXi0 + yb + 4 * j);
      yi0[4 * j] = b0.x; yi0[4 * j + 1] = b0.y; yi0[4 * j + 2] = b0.z; yi0[4 * j + 3] = b0.w;
      float4 a1 = *(const float4*)(sXr1 + yb + 4 * j);
      yr1[4 * j] = a1.x; yr1[4 * j + 1] = a1.y; yr1[4 * j + 2] = a1.z; yr1[4 * j + 3] = a1.w;
      float4 b1v = *(const float4*)(sXi1 + yb + 4 * j);
      yi1[4 * j] = b1v.x; yi1[4 * j + 1] = b1v.y; yi1[4 * j + 2] = b1v.z; yi1[4 * j + 3] = b1v.w;
    }
  }
  __syncthreads();
  if (tid < 224) {
    float zr0[4], zi0[4], zr1[4], zi1[4];
#pragma unroll
    for (int kk = 0; kk < 4; kk++) {
      int k = kq * 4 + kk;
      float2 bv = *(const float2*)(sb2 + k * 8 + wb);
      float ar0 = bv.x, ai0 = bv.y, ar1 = bv.x, ai1 = bv.y;
#pragma unroll
      for (int d = 0; d < 16; d++) {
        float2 wv = *(const float2*)(sw2 + (d * 16 + k) * 8 + wb);
        ar0 = fmaf(yr0[d], wv.x, ar0); ar0 = fmaf(-yi0[d], wv.y, ar0);
        ai0 = fmaf(yr0[d], wv.y, ai0); ai0 = fmaf(yi0[d], wv.x, ai0);
        ar1 = fmaf(yr1[d], wv.x, ar1); ar1 = fmaf(-yi1[d], wv.y, ar1);
        ai1 = fmaf(yr1[d], wv.y, ai1); ai1 = fmaf(yi1[d], wv.x, ai1);
      }
      zr0[kk] = ar0; zi0[kk] = ai0; zr1[kk] = ar1; zi1[kk] = ai1;
    }
    int yo = cw2 * S + cblk * 16 + kq * 4;
    *(float4*)(sXr0 + yo) = make_float4(zr0[0], zr0[1], zr0[2], zr0[3]);
    *(float4*)(sXi0 + yo) = make_float4(zi0[0], zi0[1], zi0[2], zi0[3]);
    *(float4*)(sXr1 + yo) = make_float4(zr1[0], zr1[1], zr1[2], zr1[3]);
    *(float4*)(sXi1 + yo) = make_float4(zi1[0], zi1[1], zi1[2], zi1[3]);
  }
  __syncthreads();

  // ---- phase 2a: read column c -> regs; barrier; token L1 -> sX [14][64]
  {
    float tr0[14], ti0[14], tr1[14], ti1[14];
#pragma unroll
    for (int d = 0; d < 14; d++) {
      tr0[d] = sXr0[d * S + c]; ti0[d] = sXi0[d * S + c];
      tr1[d] = sXr1[d * S + c]; ti1[d] = sXi1[d * S + c];
    }
    __syncthreads();
#pragma unroll
    for (int kk = 0; kk < 4; kk++) {
      int k = tkq * 4 + kk;
      if (k < 14) {
        float br = sB1[2 * k], bi = sB1[2 * k + 1];
        float ar0 = br, ai0 = bi, ar1 = br, ai1 = bi;
#pragma unroll
        for (int d = 0; d < 14; d++) {
          float wr = sT1[(d * 14 + k) * 2], wi = sT1[(d * 14 + k) * 2 + 1];
          ar0 = fmaf(tr0[d], wr, ar0); ar0 = fmaf(-ti0[d], wi, ar0);
          ai0 = fmaf(tr0[d], wi, ai0); ai0 = fmaf(ti0[d], wr, ai0);
          ar1 = fmaf(tr1[d], wr, ar1); ar1 = fmaf(-ti1[d], wi, ar1);
          ai1 = fmaf(tr1[d], wi, ai1); ai1 = fmaf(ti1[d], wr, ai1);
        }
        sXr0[k * 64 + c] = fmaxf(ar0, 0.f); sXi0[k * 64 + c] = fmaxf(ai0, 0.f);
        sXr1[k * 64 + c] = fmaxf(ar1, 0.f); sXi1[k * 64 + c] = fmaxf(ai1, 0.f);
      }
    }
  }
  __syncthreads();

  // ---- phase 2b: token L2 -> global, both tiles ----
  {
    float mr0[14], mi0[14], mr1[14], mi1[14];
#pragma unroll
    for (int d = 0; d < 14; d++) {
      mr0[d] = sXr0[d * 64 + c]; mi0[d] = sXi0[d * 64 + c];
      mr1[d] = sXr1[d * 64 + c]; mi1[d] = sXi1[d * 64 + c];
    }
#pragma unroll
    for (int kk = 0; kk < 4; kk++) {
      int k = tkq * 4 + kk;
      if (k < 14) {
        float br = sB2[2 * k], bi = sB2[2 * k + 1];
        float ar0 = br, ai0 = bi, ar1 = br, ai1 = bi;
#pragma unroll
        for (int d = 0; d < 14; d++) {
          float wr = sT2[(d * 14 + k) * 2], wi = sT2[(d * 14 + k) * 2 + 1];
          ar0 = fmaf(mr0[d], wr, ar0); ar0 = fmaf(-mi0[d], wi, ar0);
          ai0 = fmaf(mr0[d], wi, ai0); ai0 = fmaf(mi0[d], wr, ai0);
          ar1 = fmaf(mr1[d], wr, ar1); ar1 = fmaf(-mi1[d], wi, ar1);
          ai1 = fmaf(mr1[d], wi, ai1); ai1 = fmaf(mi1[d], wr, ai1);
        }
        xhr[base0 + k * 64 + c] = ar0; xhi[base0 + k * 64 + c] = ai0;
        xhr[base1 + k * 64 + c] = ar1; xhi[base1 + k * 64 + c] = ai1;
      }
    }
  }
}

// -------- K5: merged inverse column: blocks 0..1791 = A, 1792..3583 = B ----
__global__ __launch_bounds__(256) void k_invcol2(const float* __restrict__ xl,
    const float* __restrict__ xhr, const float* __restrict__ xhi,
    float* __restrict__ lo2, float* __restrict__ hi2) {
  int tid = threadIdx.x;
  int c = tid & 63;
  if (blockIdx.x < 1792) {
    // ---- A: pass 1 -> lo2 ----
    int line = blockIdx.x * 4 + (tid >> 6);    // line = b*28 + w
    int w = line % 28, b = line / 28;
    int w2 = w >> 1, pw = w & 1;
    const int hs = 28 * 64;
    int sp = (b * 784 + w) * 64 + c;
    int bb = (b * 6 * 196 + w2) * 64 + c;
    float xlv[28], lhf[28];
#pragma unroll
    for (int h = 0; h < 28; h++) xlv[h] = xl[sp + h * hs];
    const float* p0r = xhr + bb + 0 * 12544;
    const float* p0i = xhi + bb + 0 * 12544;
    const float* p5r = xhr + bb + 5 * 12544;
    const float* p5i = xhi + bb + 5 * 12544;
#pragma unroll
    for (int i = 0; i < 14; i++) {
      float y0r = p0r[i * 896], y0i = p0i[i * 896];
      float y5r = p5r[i * 896], y5i = p5i[i * 896];
      float top, bot;
      if (pw) { top = y0i + y5i; bot = y5r - y0r; }
      else    { top = y0r + y5r; bot = y0i - y5i; }
      lhf[2 * i] = top * S2C; lhf[2 * i + 1] = bot * S2C;
    }
#pragma unroll
    for (int h = 0; h < 28; h++) {
      float acc = 0.f;
#pragma unroll
      for (int t = 0; t < 19; t++) acc = fmaf(F_G0[t], xlv[refl28(h - 9 + t)], acc);
#pragma unroll
      for (int t = 0; t < 13; t++) acc = fmaf(F_G1[t], lhf[refl28(h - 6 + t)], acc);
      lo2[sp + h * hs] = acc;
    }
  } else {
    // ---- B: pass 2 -> hi2 ----
    int line = (blockIdx.x - 1792) * 4 + (tid >> 6);
    int w = line % 28, b = line / 28;
    int w2 = w >> 1, pw = w & 1;
    const int hs = 28 * 64;
    int sp = (b * 784 + w) * 64 + c;
    int bb = (b * 6 * 196 + w2) * 64 + c;
    float hlC[28], hhD[28];
    const float* p2r = xhr + bb + 2 * 12544;
    const float* p2i = xhi + bb + 2 * 12544;
    const float* p3r = xhr + bb + 3 * 12544;
    const float* p3i = xhi + bb + 3 * 12544;
#pragma unroll
    for (int i = 0; i < 14; i++) {
      float y0r = p2r[i * 896], y0i = p2i[i * 896];
      float y5r = p3r[i * 896], y5i = p3i[i * 896];
      float top, bot;
      if (pw) { top = y0i + y5i; bot = y5r - y0r; }
      else    { top = y0r + y5r; bot = y0i - y5i; }
      hlC[2 * i] = top * S2C; hlC[2 * i + 1] = bot * S2C;
    }
    const float* p1r = xhr + bb + 1 * 12544;
    const float* p1i = xhi + bb + 1 * 12544;
    const float* p4r = xhr + bb + 4 * 12544;
    const float* p4i = xhi + bb + 4 * 12544;
#pragma unroll
    for (int i = 0; i < 14; i++) {
      float y0r = p1r[i * 896], y0i = p1i[i * 896];
      float y5r = p4r[i * 896], y5i = p4i[i * 896];
      float top, bot;
      if (pw) { top = y0i + y5i; bot = y5r - y0r; }
      else    { top = y0r + y5r; bot = y0i - y5i; }
      hhD[2 * i] = top * S2C; hhD[2 * i + 1] = bot * S2C;
    }
#pragma unroll
    for (int h = 0; h < 28; h++) {
      float acc = 0.f;
#pragma unroll
      for (int t = 0; t < 19; t++) acc = fmaf(F_G0[t], hlC[refl28(h - 9 + t)], acc);
#pragma unroll
      for (int t = 0; t < 13; t++) acc = fmaf(F_G1[t], hhD[refl28(h - 6 + t)], acc);
      hi2[sp + h * hs] = acc;
    }
  }
}

// ---- K6: merged inverse row (half-lines, 0..3583) + dwconv (3584..53759) --
__global__ __launch_bounds__(256) void k_invrowdw(const float* __restrict__ lo2,
    const float* __restrict__ hi2, const float* __restrict__ x,
    const float* __restrict__ cw, const float* __restrict__ cb,
    float* __restrict__ out) {
  int tid = threadIdx.x;
  if (blockIdx.x < 3584) {
    // ---- inverse row filter, half-line per thread ----
    int c = tid & 63;
    int unit = blockIdx.x * 4 + (tid >> 6);    // [0, 14336): line*2 + half
    int line = unit >> 1;
    int half = unit & 1;                       // wave-uniform
    const float* lr = lo2 + (size_t)line * 1792 + c;
    const float* hr = hi2 + (size_t)line * 1792 + c;
    float* op = out + (size_t)line * 3584 + 64 + c;
    if (half == 0) {
      float vl[23], vh[23];                    // idx 0..22
#pragma unroll
      for (int w = 0; w < 23; w++) { vl[w] = lr[w * 64]; vh[w] = hr[w * 64]; }
#pragma unroll
      for (int w = 0; w < 14; w++) {
        float acc = 0.f;
#pragma unroll
        for (int t = 0; t < 19; t++) acc = fmaf(F_G0[t], vl[refl28(w - 9 + t)], acc);
#pragma unroll
        for (int t = 0; t < 13; t++) acc = fmaf(F_G1[t], vh[refl28(w - 6 + t)], acc);
        op[w * 128] = acc;
      }
    } else {
      float vl[23], vh[23];                    // [j] = orig [j+5]
#pragma unroll
      for (int w = 0; w < 23; w++) { vl[w] = lr[(w + 5) * 64]; vh[w] = hr[(w + 5) * 64]; }
#pragma unroll
      for (int w = 14; w < 28; w++) {
        float acc = 0.f;
#pragma unroll
        for (int t = 0; t < 19; t++) acc = fmaf(F_G0[t], vl[refl28(w - 9 + t) - 5], acc);
#pragma unroll
        for (int t = 0; t < 13; t++) acc = fmaf(F_G1[t], vh[refl28(w - 6 + t) - 5], acc);
        op[w * 128] = acc;
      }
    }
  } else {
    // ---- dwconv: depthwise 3x3, channels 0..63 ----
    int gtid = (blockIdx.x - 3584) * 256 + tid;
    int c = gtid & 63;
    int s = gtid >> 6;                 // b*784 + h*28 + w
    int w = s % 28; int t2 = s / 28; int h = t2 % 28;
    const float* k = cw + c * 9;
    const float* xb = x + (size_t)s * 128 + c;
    float acc = cb[c];
    bool hm = h > 0, hp = h < 27, wm = w > 0, wp = w < 27;
    if (hm) {
      const float* r = xb - 28 * 128;
      if (wm) acc = fmaf(r[-128], k[0], acc);
      acc = fmaf(r[0], k[1], acc);
      if (wp) acc = fmaf(r[128], k[2], acc);
    }
    if (wm) acc = fmaf(xb[-128], k[3], acc);
    acc = fmaf(xb[0], k[4], acc);
    if (wp) acc = fmaf(xb[128], k[5], acc);
    if (hp) {
      const float* r = xb + 28 * 128;
      if (wm) acc = fmaf(r[-128], k[6], acc);
      acc = fmaf(r[0], k[7], acc);
      if (wp) acc = fmaf(r[128], k[8], acc);
    }
    out[(size_t)s * 128 + c] = acc;
  }
}

// ---------------------------------------------------------------------------
extern "C" void kernel_launch(void* const* d_in, const int* in_sizes, int n_in,
                              void* d_out, int out_size, void* d_ws, size_t ws_size,
                              hipStream_t stream) {
  const float* x    = (const float*)d_in[0];
  const float* cw   = (const float*)d_in[1];
  const float* cb   = (const float*)d_in[2];
  const float* wll  = (const float*)d_in[3];
  const float* wlh1 = (const float*)d_in[4];
  const float* wlh2 = (const float*)d_in[5];
  const float* blh1 = (const float*)d_in[6];
  const float* blh2 = (const float*)d_in[7];
  const float* wt1  = (const float*)d_in[8];
  const float* wt2  = (const float*)d_in[9];
  const float* bt1  = (const float*)d_in[10];
  const float* bt2  = (const float*)d_in[11];
  float* out = (float*)d_out;
  float* ws = (float*)d_ws;

  const size_t NSP = (size_t)256 * 784 * 64;     // 12,845,056
  const size_t NXH = (size_t)256 * 6 * 196 * 64; // 19,267,584
  float* lo  = ws;              // reused as lo2 after fwdcol consumes it
  float* hi  = lo + NSP;        // reused as hi2
  float* xl  = hi + NSP;
  float* xhr = xl + NSP;
  float* xhi = xhr + NXH;       // total 308.3 MB

  dim3 blk(256);
  k_rowfilt <<<3584,  blk, 0, stream>>>(x, lo, hi);
  k_fwdcol  <<<1792,  blk, 0, stream>>>(lo, hi, wll, xl, xhr, xhi);
  k_mix     <<<10752, blk, 0, stream>>>(xhr, xhi, wlh1, wlh2, blh1, blh2,
                                        wt1, wt2, bt1, bt2);
  k_invcol2 <<<3584,  blk, 0, stream>>>(xl, xhr, xhi, lo, hi);
  k_invrowdw<<<53760, blk, 0, stream>>>(lo, hi, x, cw, cb, out);
  (void)in_sizes; (void)n_in; (void)out_size; (void)ws_size;
}